// Round 1
// baseline (1401.808 us; speedup 1.0000x reference)
//
#include <hip/hip_runtime.h>
#include <hip/hip_bf16.h>

// GCN link predictor:
//   h1 = x @ W1                      [100000,256]x[256,64]
//   z1 = relu(spmm(A, h1) + b1)      A: 3.2M nnz COO, atomic scatter
//   h2 = z1 @ W2                     [100000,64]x[64,32]
//   z2 = spmm(A, h2) + b2
//   scores[e] = dot(z2[src_e], z2[dst_e])   2M edges
//
// Round 1: correct fp32 baseline. SPMM via per-element atomicAdd (expected
// bottleneck); GEMM1 with W1 staged in LDS + 4x4 register microtile.

#define D_IN  256
#define D_HID 64
#define D_EMB 32

// ---------------------------------------------------------------------------
// GEMM1: h1[M,64] = x[M,256] @ W1[256,64]
// Block = 256 threads = 16x16; block tile = 64 rows x 64 cols; thread = 4x4.
// W1 (64 KB) fully staged in LDS.
__global__ __launch_bounds__(256) void gemm1_kernel(
    const float* __restrict__ x, const float* __restrict__ W1,
    float* __restrict__ h1, int M) {
  __shared__ float ws[D_IN * D_HID];  // [k][c], 64 KB
  const int tid = threadIdx.x;
  // cooperative load of W1 (4096 float4)
  for (int i = tid; i < D_IN * D_HID / 4; i += 256) {
    ((float4*)ws)[i] = ((const float4*)W1)[i];
  }
  __syncthreads();

  const int row0 = blockIdx.x * 64;
  const int tr = tid >> 4;   // 0..15 -> rows tr*4..tr*4+3? no: 4 rows strided
  const int tc = tid & 15;   // 0..15 -> cols tc*4..tc*4+3

  // thread rows: row0 + tr + 16*i, i in 0..3
  int rows[4];
  int rload[4];
  for (int i = 0; i < 4; ++i) {
    rows[i] = row0 + tr + 16 * i;
    rload[i] = rows[i] < M ? rows[i] : (M - 1);  // clamp for safe loads
  }

  float acc[4][4];
  for (int i = 0; i < 4; ++i)
    for (int j = 0; j < 4; ++j) acc[i][j] = 0.f;

  for (int k0 = 0; k0 < D_IN; k0 += 4) {
    float4 xv[4];
    for (int i = 0; i < 4; ++i)
      xv[i] = *(const float4*)&x[(long long)rload[i] * D_IN + k0];
    for (int kk = 0; kk < 4; ++kk) {
      const float4 wv = *(const float4*)&ws[(k0 + kk) * D_HID + tc * 4];
      for (int i = 0; i < 4; ++i) {
        const float a = (kk == 0) ? xv[i].x : (kk == 1) ? xv[i].y
                       : (kk == 2) ? xv[i].z : xv[i].w;
        acc[i][0] += a * wv.x;
        acc[i][1] += a * wv.y;
        acc[i][2] += a * wv.z;
        acc[i][3] += a * wv.w;
      }
    }
  }

  for (int i = 0; i < 4; ++i) {
    if (rows[i] < M) {
      float4 o = make_float4(acc[i][0], acc[i][1], acc[i][2], acc[i][3]);
      *(float4*)&h1[(long long)rows[i] * D_HID + tc * 4] = o;
    }
  }
}

// ---------------------------------------------------------------------------
// SPMM: out[dst[e]*D + d] += val[e] * in[src[e]*D + d]   (atomic)
// One thread per (edge, dim).
template <int D>
__global__ __launch_bounds__(256) void spmm_kernel(
    const int* __restrict__ src, const int* __restrict__ dst,
    const float* __restrict__ val, const float* __restrict__ in,
    float* __restrict__ out, int nnz) {
  const long long t = (long long)blockIdx.x * blockDim.x + threadIdx.x;
  const int e = (int)(t / D);
  const int d = (int)(t % D);
  if (e >= nnz) return;
  const float v = val[e];
  const int s = src[e];
  const int dd = dst[e];
  atomicAdd(&out[(long long)dd * D + d], v * in[(long long)s * D + d]);
}

// ---------------------------------------------------------------------------
// GEMM2: h2[M,32] = relu(z1[M,64] + b1) @ W2[64,32]
// One thread per row; W2 (8 KB) + b1 in LDS; relu+bias fused into A-read.
__global__ __launch_bounds__(256) void gemm2_kernel(
    const float* __restrict__ z1, const float* __restrict__ b1,
    const float* __restrict__ W2, float* __restrict__ h2, int M) {
  __shared__ float ws[D_HID * D_EMB];  // [k][c], 8 KB
  __shared__ float b1s[D_HID];
  const int tid = threadIdx.x;
  for (int i = tid; i < D_HID * D_EMB / 4; i += 256)
    ((float4*)ws)[i] = ((const float4*)W2)[i];
  if (tid < D_HID) b1s[tid] = b1[tid];
  __syncthreads();

  const int row = blockIdx.x * 256 + tid;
  if (row >= M) return;

  float4 acc4[8];
  for (int c = 0; c < 8; ++c) acc4[c] = make_float4(0.f, 0.f, 0.f, 0.f);

  for (int k0 = 0; k0 < D_HID; k0 += 4) {
    float4 zv = *(const float4*)&z1[(long long)row * D_HID + k0];
    float a0 = fmaxf(zv.x + b1s[k0 + 0], 0.f);
    float a1 = fmaxf(zv.y + b1s[k0 + 1], 0.f);
    float a2 = fmaxf(zv.z + b1s[k0 + 2], 0.f);
    float a3 = fmaxf(zv.w + b1s[k0 + 3], 0.f);
    float av[4] = {a0, a1, a2, a3};
    for (int kk = 0; kk < 4; ++kk) {
      const float a = av[kk];
      const float4* wr = (const float4*)&ws[(k0 + kk) * D_EMB];
      for (int c = 0; c < 8; ++c) {
        float4 wv = wr[c];  // wave-uniform address -> broadcast
        acc4[c].x += a * wv.x;
        acc4[c].y += a * wv.y;
        acc4[c].z += a * wv.z;
        acc4[c].w += a * wv.w;
      }
    }
  }
  float4* outp = (float4*)&h2[(long long)row * D_EMB];
  for (int c = 0; c < 8; ++c) outp[c] = acc4[c];
}

// ---------------------------------------------------------------------------
// Decoder: scores[e] = dot(z2[src]+b2, z2[dst]+b2), 32 dims.
__global__ __launch_bounds__(256) void decode_kernel(
    const int* __restrict__ ei, const float* __restrict__ z2,
    const float* __restrict__ b2, float* __restrict__ out, int nE) {
  __shared__ float b2s[D_EMB];
  if (threadIdx.x < D_EMB) b2s[threadIdx.x] = b2[threadIdx.x];
  __syncthreads();
  const int e = blockIdx.x * 256 + threadIdx.x;
  if (e >= nE) return;
  const int s = ei[e];
  const int d = ei[nE + e];
  const float4* za = (const float4*)&z2[(long long)s * D_EMB];
  const float4* zb = (const float4*)&z2[(long long)d * D_EMB];
  const float4* bb = (const float4*)b2s;
  float acc = 0.f;
  for (int c = 0; c < 8; ++c) {
    float4 a = za[c], b = zb[c], bv = bb[c];
    acc += (a.x + bv.x) * (b.x + bv.x);
    acc += (a.y + bv.y) * (b.y + bv.y);
    acc += (a.z + bv.z) * (b.z + bv.z);
    acc += (a.w + bv.w) * (b.w + bv.w);
  }
  out[e] = acc;
}

// ---------------------------------------------------------------------------
extern "C" void kernel_launch(void* const* d_in, const int* in_sizes, int n_in,
                              void* d_out, int out_size, void* d_ws, size_t ws_size,
                              hipStream_t stream) {
  const float* x       = (const float*)d_in[0];
  const int*   adj_src = (const int*)d_in[1];
  const int*   adj_dst = (const int*)d_in[2];
  const float* adj_val = (const float*)d_in[3];
  const int*   ei      = (const int*)d_in[4];
  const float* W1      = (const float*)d_in[5];
  const float* b1      = (const float*)d_in[6];
  const float* W2      = (const float*)d_in[7];
  const float* b2      = (const float*)d_in[8];

  const int M   = in_sizes[0] / D_IN;      // 100000
  const int nnz = in_sizes[1];             // 3200000
  const int nE  = in_sizes[4] / 2;         // 2000000

  char* ws = (char*)d_ws;
  float* h1 = (float*)(ws);                                   // M*64 f32
  float* z1 = (float*)(ws + (size_t)M * D_HID * 4);           // M*64 f32
  float* h2 = (float*)(ws + (size_t)M * D_HID * 8);           // M*32 f32
  float* z2 = (float*)(ws + (size_t)M * D_HID * 8 + (size_t)M * D_EMB * 4);

  // zero the atomic-accumulation buffers
  hipMemsetAsync(z1, 0, (size_t)M * D_HID * 4, stream);
  hipMemsetAsync(z2, 0, (size_t)M * D_EMB * 4, stream);

  // GEMM1
  gemm1_kernel<<<(M + 63) / 64, 256, 0, stream>>>(x, W1, h1, M);

  // SPMM1 (d=64)
  {
    long long threads = (long long)nnz * D_HID;
    int blocks = (int)((threads + 255) / 256);
    spmm_kernel<D_HID><<<blocks, 256, 0, stream>>>(adj_src, adj_dst, adj_val,
                                                   h1, z1, nnz);
  }

  // GEMM2 (relu+b1 fused)
  gemm2_kernel<<<(M + 255) / 256, 256, 0, stream>>>(z1, b1, W2, h2, M);

  // SPMM2 (d=32)
  {
    long long threads = (long long)nnz * D_EMB;
    int blocks = (int)((threads + 255) / 256);
    spmm_kernel<D_EMB><<<blocks, 256, 0, stream>>>(adj_src, adj_dst, adj_val,
                                                   h2, z2, nnz);
  }

  // Decoder (b2 fused)
  decode_kernel<<<(nE + 255) / 256, 256, 0, stream>>>(ei, z2, b2, (float*)d_out, nE);
}

// Round 2
// 946.384 us; speedup vs baseline: 1.4812x; 1.4812x over previous
//
#include <hip/hip_runtime.h>
#include <hip/hip_bf16.h>

// GCN link predictor, Round 2: atomic-free SPMM via device-built CSR.
//   h1 = x @ W1                      [100000,256]x[256,64]
//   z1 = relu(csr_spmm(A, h1) + b1)  (bias+relu fused in SPMM epilogue)
//   h2 = z1 @ W2                     [100000,64]x[64,32]
//   z2 = csr_spmm(A, h2) + b2        (bias fused)
//   scores[e] = dot(z2[src_e], z2[dst_e])
//
// CSR build (per call, graph-capture safe): histogram -> 3-kernel exclusive
// scan (in-place) -> scatter. Scatter's atomicAdd on the exclusive-scan array
// converts it in place to the inclusive scan, so row i's segment is
// [rs[i-1], rs[i]) with rs[-1]=0 — no separate cursor array.
// Scan/rowstart scratch (0.4 MB) lives in d_out (dead until decode).

#define D_IN  256
#define D_HID 64
#define D_EMB 32
#define SCAN_CHUNK 2048  // 256 threads x 8 elements

// ---------------------------------------------------------------------------
// GEMM1: h1[M,64] = x[M,256] @ W1[256,64]. W1 (64 KB) in LDS, 4x4 microtile.
__global__ __launch_bounds__(256) void gemm1_kernel(
    const float* __restrict__ x, const float* __restrict__ W1,
    float* __restrict__ h1, int M) {
  __shared__ float ws[D_IN * D_HID];
  const int tid = threadIdx.x;
  for (int i = tid; i < D_IN * D_HID / 4; i += 256)
    ((float4*)ws)[i] = ((const float4*)W1)[i];
  __syncthreads();

  const int row0 = blockIdx.x * 64;
  const int tr = tid >> 4;
  const int tc = tid & 15;

  int rows[4], rload[4];
  for (int i = 0; i < 4; ++i) {
    rows[i] = row0 + tr + 16 * i;
    rload[i] = rows[i] < M ? rows[i] : (M - 1);
  }

  float acc[4][4];
  for (int i = 0; i < 4; ++i)
    for (int j = 0; j < 4; ++j) acc[i][j] = 0.f;

  for (int k0 = 0; k0 < D_IN; k0 += 4) {
    float4 xv[4];
    for (int i = 0; i < 4; ++i)
      xv[i] = *(const float4*)&x[(long long)rload[i] * D_IN + k0];
    for (int kk = 0; kk < 4; ++kk) {
      const float4 wv = *(const float4*)&ws[(k0 + kk) * D_HID + tc * 4];
      for (int i = 0; i < 4; ++i) {
        const float a = (kk == 0) ? xv[i].x : (kk == 1) ? xv[i].y
                       : (kk == 2) ? xv[i].z : xv[i].w;
        acc[i][0] += a * wv.x;
        acc[i][1] += a * wv.y;
        acc[i][2] += a * wv.z;
        acc[i][3] += a * wv.w;
      }
    }
  }
  for (int i = 0; i < 4; ++i)
    if (rows[i] < M)
      *(float4*)&h1[(long long)rows[i] * D_HID + tc * 4] =
          make_float4(acc[i][0], acc[i][1], acc[i][2], acc[i][3]);
}

// ---------------------------------------------------------------------------
// CSR build
__global__ __launch_bounds__(256) void count_kernel(
    const int* __restrict__ dst, int* __restrict__ deg, int nnz) {
  int e = blockIdx.x * 256 + threadIdx.x;
  if (e < nnz) atomicAdd(&deg[dst[e]], 1);
}

__global__ __launch_bounds__(256) void scan_reduce(
    const int* __restrict__ deg, int* __restrict__ partials, int N) {
  __shared__ int sm[256];
  int base = blockIdx.x * SCAN_CHUNK + threadIdx.x * 8;
  int s = 0;
  for (int i = 0; i < 8; ++i) {
    int idx = base + i;
    if (idx < N) s += deg[idx];
  }
  sm[threadIdx.x] = s;
  __syncthreads();
  for (int off = 128; off > 0; off >>= 1) {
    if (threadIdx.x < off) sm[threadIdx.x] += sm[threadIdx.x + off];
    __syncthreads();
  }
  if (threadIdx.x == 0) partials[blockIdx.x] = sm[0];
}

__global__ void scan_partials(int* partials, int NB) {
  if (threadIdx.x == 0) {
    int run = 0;
    for (int b = 0; b < NB; ++b) {
      int v = partials[b];
      partials[b] = run;
      run += v;
    }
  }
}

// In-place: reads deg[idx], writes exclusive prefix to same array (each
// element read and written only by its own thread; block-local barriers only).
__global__ __launch_bounds__(256) void scan_downsweep(
    int* __restrict__ deg_rs, const int* __restrict__ partials, int N) {
  __shared__ int sm[256];
  const int t = threadIdx.x;
  const int base = blockIdx.x * SCAN_CHUNK + t * 8;
  int loc[8];
  int s = 0;
  int v[8];
  for (int i = 0; i < 8; ++i) {
    int idx = base + i;
    v[i] = (idx < N) ? deg_rs[idx] : 0;
    loc[i] = s;
    s += v[i];
  }
  sm[t] = s;
  __syncthreads();
  // inclusive Hillis-Steele over thread sums
  for (int off = 1; off < 256; off <<= 1) {
    int tmp = (t >= off) ? sm[t - off] : 0;
    __syncthreads();
    sm[t] += tmp;
    __syncthreads();
  }
  const int off0 = partials[blockIdx.x] + sm[t] - s;  // exclusive thread base
  for (int i = 0; i < 8; ++i) {
    int idx = base + i;
    if (idx < N) deg_rs[idx] = off0 + loc[i];
  }
}

// Scatter; converts rs (exclusive) -> rs (inclusive) as a side effect.
__global__ __launch_bounds__(256) void scatter_kernel(
    const int* __restrict__ src, const int* __restrict__ dst,
    const float* __restrict__ val, int* __restrict__ rs,
    int* __restrict__ csr_src, float* __restrict__ csr_val, int nnz) {
  int e = blockIdx.x * 256 + threadIdx.x;
  if (e >= nnz) return;
  int p = atomicAdd(&rs[dst[e]], 1);
  csr_src[p] = src[e];
  csr_val[p] = val[e];
}

// ---------------------------------------------------------------------------
// CSR SPMM: out[row][d] = epilogue( sum_{j in row} val[j]*in[src[j]][d] )
// One D-lane team per row; rs is the INCLUSIVE scan (end of row i = rs[i]).
template <int D, bool RELU>
__global__ __launch_bounds__(256) void spmm_csr_kernel(
    const int* __restrict__ rs, const int* __restrict__ csr_src,
    const float* __restrict__ csr_val, const float* __restrict__ in,
    const float* __restrict__ bias, float* __restrict__ out, int M) {
  const int lane = threadIdx.x % D;
  const int row = blockIdx.x * (256 / D) + threadIdx.x / D;
  if (row >= M) return;
  const int start = (row == 0) ? 0 : rs[row - 1];
  const int end = rs[row];
  float acc = 0.f;
  int j = start;
  for (; j + 2 <= end; j += 2) {
    int s0 = csr_src[j], s1 = csr_src[j + 1];
    float v0 = csr_val[j], v1 = csr_val[j + 1];
    float x0 = in[(long long)s0 * D + lane];
    float x1 = in[(long long)s1 * D + lane];
    acc = fmaf(v0, x0, acc);
    acc = fmaf(v1, x1, acc);
  }
  if (j < end) {
    int s0 = csr_src[j];
    float v0 = csr_val[j];
    acc = fmaf(v0, in[(long long)s0 * D + lane], acc);
  }
  float r = acc + bias[lane];
  if (RELU) r = fmaxf(r, 0.f);
  out[(long long)row * D + lane] = r;
}

// ---------------------------------------------------------------------------
// GEMM2: h2[M,32] = z1[M,64] @ W2[64,32] (z1 already has bias+relu applied)
__global__ __launch_bounds__(256) void gemm2_kernel(
    const float* __restrict__ z1, const float* __restrict__ W2,
    float* __restrict__ h2, int M) {
  __shared__ float ws[D_HID * D_EMB];
  const int tid = threadIdx.x;
  for (int i = tid; i < D_HID * D_EMB / 4; i += 256)
    ((float4*)ws)[i] = ((const float4*)W2)[i];
  __syncthreads();

  const int row = blockIdx.x * 256 + tid;
  if (row >= M) return;

  float4 acc4[8];
  for (int c = 0; c < 8; ++c) acc4[c] = make_float4(0.f, 0.f, 0.f, 0.f);

  for (int k0 = 0; k0 < D_HID; k0 += 4) {
    float4 zv = *(const float4*)&z1[(long long)row * D_HID + k0];
    float av[4] = {zv.x, zv.y, zv.z, zv.w};
    for (int kk = 0; kk < 4; ++kk) {
      const float a = av[kk];
      const float4* wr = (const float4*)&ws[(k0 + kk) * D_EMB];
      for (int c = 0; c < 8; ++c) {
        float4 wv = wr[c];
        acc4[c].x += a * wv.x;
        acc4[c].y += a * wv.y;
        acc4[c].z += a * wv.z;
        acc4[c].w += a * wv.w;
      }
    }
  }
  float4* outp = (float4*)&h2[(long long)row * D_EMB];
  for (int c = 0; c < 8; ++c) outp[c] = acc4[c];
}

// ---------------------------------------------------------------------------
// Decoder: scores[e] = dot(z2[src], z2[dst])  (b2 already in z2)
__global__ __launch_bounds__(256) void decode_kernel(
    const int* __restrict__ ei, const float* __restrict__ z2,
    float* __restrict__ out, int nE) {
  const int e = blockIdx.x * 256 + threadIdx.x;
  if (e >= nE) return;
  const int s = ei[e];
  const int d = ei[nE + e];
  const float4* za = (const float4*)&z2[(long long)s * D_EMB];
  const float4* zb = (const float4*)&z2[(long long)d * D_EMB];
  float acc = 0.f;
  for (int c = 0; c < 8; ++c) {
    float4 a = za[c], b = zb[c];
    acc += a.x * b.x + a.y * b.y + a.z * b.z + a.w * b.w;
  }
  out[e] = acc;
}

// ---------------------------------------------------------------------------
extern "C" void kernel_launch(void* const* d_in, const int* in_sizes, int n_in,
                              void* d_out, int out_size, void* d_ws, size_t ws_size,
                              hipStream_t stream) {
  const float* x       = (const float*)d_in[0];
  const int*   adj_src = (const int*)d_in[1];
  const int*   adj_dst = (const int*)d_in[2];
  const float* adj_val = (const float*)d_in[3];
  const int*   ei      = (const int*)d_in[4];
  const float* W1      = (const float*)d_in[5];
  const float* b1      = (const float*)d_in[6];
  const float* W2      = (const float*)d_in[7];
  const float* b2      = (const float*)d_in[8];

  const int M   = in_sizes[0] / D_IN;      // 100000
  const int nnz = in_sizes[1];             // 3200000
  const int nE  = in_sizes[4] / 2;         // 2000000

  // Workspace layout (76.8 MB):
  //   [0, 25.6 MB):      h1 (M*64 f32); later reused for h2 (M*32 f32)
  //   [25.6, 51.2 MB):   z1 (M*64 f32); later reused for z2 (M*32 f32)
  //   [51.2, 64.0 MB):   csr_src (nnz i32)
  //   [64.0, 76.8 MB):   csr_val (nnz f32)
  char* ws = (char*)d_ws;
  float* h1      = (float*)(ws);
  float* z1      = (float*)(ws + (size_t)M * D_HID * 4);
  float* h2      = h1;   // h1 dead after SPMM1
  float* z2      = z1;   // z1 dead after GEMM2
  int*   csr_src = (int*)(ws + (size_t)M * D_HID * 8);
  float* csr_val = (float*)(ws + (size_t)M * D_HID * 8 + (size_t)nnz * 4);

  // Scan scratch in d_out (dead until decode overwrites it):
  //   rs: M ints @ 0; partials: NB ints @ M (aligned up)
  int* rs       = (int*)d_out;
  int* partials = (int*)d_out + ((M + 255) & ~255);
  const int NB = (M + SCAN_CHUNK - 1) / SCAN_CHUNK;  // 49

  // --- CSR build ---
  hipMemsetAsync(rs, 0, (size_t)M * 4, stream);
  count_kernel<<<(nnz + 255) / 256, 256, 0, stream>>>(adj_dst, rs, nnz);
  scan_reduce<<<NB, 256, 0, stream>>>(rs, partials, M);
  scan_partials<<<1, 64, 0, stream>>>(partials, NB);
  scan_downsweep<<<NB, 256, 0, stream>>>(rs, partials, M);
  scatter_kernel<<<(nnz + 255) / 256, 256, 0, stream>>>(
      adj_src, adj_dst, adj_val, rs, csr_src, csr_val, nnz);
  // rs is now the inclusive scan: row i = [rs[i-1], rs[i])

  // --- GEMM1 ---
  gemm1_kernel<<<(M + 63) / 64, 256, 0, stream>>>(x, W1, h1, M);

  // --- SPMM1 + b1 + ReLU ---
  spmm_csr_kernel<D_HID, true><<<(M + 3) / 4, 256, 0, stream>>>(
      rs, csr_src, csr_val, h1, b1, z1, M);

  // --- GEMM2 ---
  gemm2_kernel<<<(M + 255) / 256, 256, 0, stream>>>(z1, W2, h2, M);

  // --- SPMM2 + b2 ---
  spmm_csr_kernel<D_EMB, false><<<(M + 7) / 8, 256, 0, stream>>>(
      rs, csr_src, csr_val, h2, b2, z2, M);

  // --- Decode (overwrites d_out scratch) ---
  decode_kernel<<<(nE + 255) / 256, 256, 0, stream>>>(ei, z2, (float*)d_out, nE);
}